// Round 2
// baseline (449.938 us; speedup 1.0000x reference)
//
#include <hip/hip_runtime.h>
#include <math.h>

#define NUM_CLASSES 80
#define F4_PER_ROW  20
#define THREADS     256
#define NBLOCKS     2048
#define ROWS_PER_ITER 128   // two 64-row halves per block-iteration (quad per row)

constexpr float ALPHA = 0.25f;
constexpr float CENTER_W = 0.1f;
constexpr float EPS_GIOU = 1e-7f;

typedef float f32x4 __attribute__((ext_vector_type(4)));

// ---------------------------------------------------------------------------
// Per-row focal-loss contribution. Quad (4 lanes) holds the 80-float row in
// v[5] (lane c owns elements 16j + 4c + comp). All 4 lanes participate in the
// shuffles; only lane-in-quad 0 of a live row returns nonzero.
// ---------------------------------------------------------------------------
__device__ __forceinline__ float focal_row(const f32x4 v[5], int gc, bool live, int t)
{
    // quad max
    float m = -INFINITY;
    #pragma unroll
    for (int j = 0; j < 5; ++j)
        m = fmaxf(m, fmaxf(fmaxf(v[j].x, v[j].y), fmaxf(v[j].z, v[j].w)));
    m = fmaxf(m, __shfl_xor(m, 1, 64));
    m = fmaxf(m, __shfl_xor(m, 2, 64));

    // quad sum-exp
    float s = 0.0f;
    #pragma unroll
    for (int j = 0; j < 5; ++j) {
        s += __expf(v[j].x - m);
        s += __expf(v[j].y - m);
        s += __expf(v[j].z - m);
        s += __expf(v[j].w - m);
    }
    s += __shfl_xor(s, 1, 64);
    s += __shfl_xor(s, 2, 64);

    // extract x[gc]: owner lane-in-quad = (gc>>2)&3, reg j = gc>>4, comp = gc&3
    const int j_src = gc >> 4;
    const int comp  = gc & 3;
    float sel = 0.0f;
    #pragma unroll
    for (int j = 0; j < 5; ++j) {
        const f32x4 vv = v[j];
        const float cand = (comp == 0) ? vv.x :
                           (comp == 1) ? vv.y :
                           (comp == 2) ? vv.z : vv.w;
        sel = (j == j_src) ? cand : sel;
    }
    const int lane = t & 63;
    const float xg = __shfl(sel, (lane & ~3) | ((gc >> 2) & 3), 64);

    const float lse = m + __logf(s);
    const float ce  = lse - xg;
    const float pt  = __expf(-ce);
    const float omp = 1.0f - pt;
    return (live && (t & 3) == 0) ? (ALPHA * omp * omp * ce) : 0.0f;
}

// ---------------------------------------------------------------------------
// Kernel 1: Phase A: quad-per-row softmax/focal, TWO rows in flight per quad
//           (12 loads issued before any dependent use -> deeper MLP).
//           Phase B: thread-per-row GIoU + centerness (coalesced float4).
// ---------------------------------------------------------------------------
__global__ __launch_bounds__(THREADS) void hdm_loss_kernel(
    const float* __restrict__ cls_logits,   // (N, 80)
    const float* __restrict__ bbox_reg,     // (N, 4)
    const float* __restrict__ centerness,   // (N,)
    const float* __restrict__ gt_bboxes,    // (N, 4)
    const int*   __restrict__ gt_classes,   // (N,)
    double* __restrict__ partials,          // (NBLOCKS, 3)
    int n)
{
    const int t = threadIdx.x;
    double f_acc = 0.0, g_acc = 0.0, c_acc = 0.0;

    // ================= Phase A: focal loss, quad (4 lanes) per row =========
    {
        const int q = t >> 2;          // quad id within block: 0..63
        const int c = t & 3;           // lane within quad
        const f32x4* src = (const f32x4*)cls_logits;
        const f32x4 zero = {0.f, 0.f, 0.f, 0.f};

        for (int rb = blockIdx.x * ROWS_PER_ITER; rb < n;
             rb += NBLOCKS * ROWS_PER_ITER) {
            const int r0 = rb + q;            // first 64-row half
            const int r1 = rb + 64 + q;       // second 64-row half
            const bool live0 = (r0 < n);
            const bool live1 = (r1 < n);

            // issue the small loads first so the row-0 wait leaves row-1's
            // vector loads outstanding
            const int gc0 = live0 ? gt_classes[r0] : 0;
            const int gc1 = live1 ? gt_classes[r1] : 0;

            f32x4 v0[5], v1[5];
            const long b0 = (long)r0 * F4_PER_ROW + c;
            const long b1 = (long)r1 * F4_PER_ROW + c;
            #pragma unroll
            for (int j = 0; j < 5; ++j)
                v0[j] = live0 ? src[b0 + j * 4] : zero;
            #pragma unroll
            for (int j = 0; j < 5; ++j)
                v1[j] = live1 ? src[b1 + j * 4] : zero;

            f_acc += (double)focal_row(v0, gc0, live0, t);
            f_acc += (double)focal_row(v1, gc1, live1, t);
        }
    }

    // ================= Phase B: GIoU + centerness, thread per row ==========
    {
        const f32x4* pb = (const f32x4*)bbox_reg;
        const f32x4* gb = (const f32x4*)gt_bboxes;
        for (int i = blockIdx.x * THREADS + t; i < n; i += NBLOCKS * THREADS) {
            const f32x4 p = pb[i];
            const f32x4 g = gb[i];
            const float iw = fmaxf(fminf(p.z, g.z) - fmaxf(p.x, g.x), 0.0f);
            const float ih = fmaxf(fminf(p.w, g.w) - fmaxf(p.y, g.y), 0.0f);
            const float inter  = iw * ih;
            const float area_p = (p.z - p.x) * (p.w - p.y);
            const float area_g = (g.z - g.x) * (g.w - g.y);
            const float uni    = area_p + area_g - inter;
            const float iou    = inter / (uni + EPS_GIOU);
            const float cw = fmaxf(p.z, g.z) - fminf(p.x, g.x);
            const float ch = fmaxf(p.w, g.w) - fminf(p.y, g.y);
            const float area_c = cw * ch;
            const float giou = iou - (area_c - uni) / (area_c + EPS_GIOU);
            g_acc += (double)(1.0f - giou);

            const float cc = centerness[i];
            c_acc += (double)(fmaxf(-cc, 0.0f) + log1pf(__expf(-fabsf(cc))));
        }
    }

    // ================= block reduction (double) ============================
    #pragma unroll
    for (int off = 32; off > 0; off >>= 1) {
        f_acc += __shfl_down(f_acc, off, 64);
        g_acc += __shfl_down(g_acc, off, 64);
        c_acc += __shfl_down(c_acc, off, 64);
    }
    __shared__ double sf[4], sg[4], sc[4];
    const int lane = t & 63;
    const int wave = t >> 6;
    if (lane == 0) { sf[wave] = f_acc; sg[wave] = g_acc; sc[wave] = c_acc; }
    __syncthreads();
    if (t == 0) {
        partials[blockIdx.x * 3 + 0] = sf[0] + sf[1] + sf[2] + sf[3];
        partials[blockIdx.x * 3 + 1] = sg[0] + sg[1] + sg[2] + sg[3];
        partials[blockIdx.x * 3 + 2] = sc[0] + sc[1] + sc[2] + sc[3];
    }
}

// ---------------------------------------------------------------------------
// Kernel 2: reduce partials, write the 4 output scalars
// ---------------------------------------------------------------------------
__global__ __launch_bounds__(256) void hdm_finalize_kernel(
    const double* __restrict__ partials, int nblocks, int n,
    float* __restrict__ out)
{
    double f = 0.0, g = 0.0, c = 0.0;
    for (int i = threadIdx.x; i < nblocks; i += 256) {
        f += partials[i * 3 + 0];
        g += partials[i * 3 + 1];
        c += partials[i * 3 + 2];
    }
    #pragma unroll
    for (int off = 32; off > 0; off >>= 1) {
        f += __shfl_down(f, off, 64);
        g += __shfl_down(g, off, 64);
        c += __shfl_down(c, off, 64);
    }
    __shared__ double sf[4], sg[4], sc[4];
    const int lane = threadIdx.x & 63;
    const int wave = threadIdx.x >> 6;
    if (lane == 0) { sf[wave] = f; sg[wave] = g; sc[wave] = c; }
    __syncthreads();
    if (threadIdx.x == 0) {
        double tf = 0.0, tg = 0.0, tc = 0.0;
        #pragma unroll
        for (int w = 0; w < 4; ++w) { tf += sf[w]; tg += sg[w]; tc += sc[w]; }
        const double inv_n = 1.0 / (double)n;
        const double focal_mean  = tf * inv_n;
        const double iou_mean    = tg * inv_n;
        const double center_mean = tc * inv_n;
        const double total = focal_mean + iou_mean + (double)CENTER_W * center_mean;
        out[0] = (float)total;
        out[1] = (float)focal_mean;
        out[2] = (float)iou_mean;
        out[3] = (float)center_mean;
    }
}

extern "C" void kernel_launch(void* const* d_in, const int* in_sizes, int n_in,
                              void* d_out, int out_size, void* d_ws, size_t ws_size,
                              hipStream_t stream) {
    const float* cls_logits = (const float*)d_in[0];
    const float* bbox_reg   = (const float*)d_in[1];
    const float* centerness = (const float*)d_in[2];
    const float* gt_bboxes  = (const float*)d_in[3];
    const int*   gt_classes = (const int*)d_in[4];
    float* out = (float*)d_out;

    const int n = in_sizes[2];              // N
    double* partials = (double*)d_ws;       // NBLOCKS*3*8B = 48 KB

    hdm_loss_kernel<<<NBLOCKS, THREADS, 0, stream>>>(
        cls_logits, bbox_reg, centerness, gt_bboxes, gt_classes, partials, n);
    hdm_finalize_kernel<<<1, 256, 0, stream>>>(partials, NBLOCKS, n, out);
}